// Round 1
// 74.908 us; speedup vs baseline: 1.3154x; 1.3154x over previous
//
#include <hip/hip_runtime.h>
#include <hip/hip_bf16.h>

#define Bv 8
#define Nv 512
#define Dv 1024
#define Ev 8
#define Hv 8
#define HDv 128
#define EPSv 1e-5f

typedef __attribute__((ext_vector_type(8))) short short8;
typedef __attribute__((ext_vector_type(4))) float f32x4;

__device__ __forceinline__ unsigned short f2b(float f) {
    __hip_bfloat16 h = __float2bfloat16(f);
    return *reinterpret_cast<unsigned short*>(&h);
}
__device__ __forceinline__ float bf2f(unsigned int u) {
    union { unsigned int i; float f; } v; v.i = u << 16; return v.f;
}
__device__ __forceinline__ unsigned int blend2(unsigned int a, unsigned int b,
                                               float tw0, float tw1) {
    float lo = tw0 * bf2f(a & 0xffffu) + tw1 * bf2f(b & 0xffffu);
    float hi = tw0 * bf2f(a >> 16)     + tw1 * bf2f(b >> 16);
    return (unsigned int)f2b(lo) | ((unsigned int)f2b(hi) << 16);
}

// async global->LDS, 16 bytes per lane; LDS dest must be linear (base + lane*16)
__device__ __forceinline__ void gld16(const void* g, void* l) {
    __builtin_amdgcn_global_load_lds(
        (const __attribute__((address_space(1))) void*)(uintptr_t)(g),
        (__attribute__((address_space(3))) void*)(uintptr_t)(l), 16, 0, 0);
}

// ---------------- fused preprocessing:
//   blocks [0,128):        cast x->bf16 + column mean (xmean)
//   blocks [128,8320):     softmax all E*H*N weight rows -> wa bf16
//   blocks [8320,9344):    cast in_w/out_w -> bf16
__global__ __launch_bounds__(256) void k_pre(const float* __restrict__ x,
                                             const float* __restrict__ weight,
                                             const float* __restrict__ w1,
                                             const float* __restrict__ w2,
                                             unsigned short* __restrict__ xb,
                                             float* __restrict__ xmean,
                                             unsigned short* __restrict__ wa,
                                             unsigned short* __restrict__ w1b,
                                             unsigned short* __restrict__ w2b) {
    int bid = blockIdx.x;
    if (bid < 128) {
        __shared__ float ps[4][64];
        int b = bid >> 4;
        int d0 = (bid & 15) << 6;
        int dt = threadIdx.x & 63;
        int pg = threadIdx.x >> 6;         // 4 n-partitions
        const float* p = x + (size_t)b * Nv * Dv + d0 + dt;
        unsigned short* q = xb + (size_t)b * Nv * Dv + d0 + dt;
        float s = 0.f;
        for (int n = pg * 128; n < pg * 128 + 128; ++n) {
            float v = p[(size_t)n * Dv];
            s += v;
            q[(size_t)n * Dv] = f2b(v);
        }
        ps[pg][dt] = s;
        __syncthreads();
        if (threadIdx.x < 64) {
            float tt = ps[0][dt] + ps[1][dt] + ps[2][dt] + ps[3][dt];
            xmean[b * Dv + d0 + dt] = tt * (1.f / Nv);
        }
        return;
    }
    if (bid < 128 + 8192) {
        int wave = (bid - 128) * 4 + (threadIdx.x >> 6);  // row over E*H*N = 32768
        int lane = threadIdx.x & 63;
        const float* row = weight + (size_t)wave * Nv;
        const float4* r4 = (const float4*)(row + lane * 8);
        float4 a = r4[0], b = r4[1];
        float v[8] = {a.x, a.y, a.z, a.w, b.x, b.y, b.z, b.w};
        float mx = v[0];
        #pragma unroll
        for (int i = 1; i < 8; ++i) mx = fmaxf(mx, v[i]);
        for (int off = 1; off < 64; off <<= 1) mx = fmaxf(mx, __shfl_xor(mx, off));
        float s = 0.f;
        #pragma unroll
        for (int i = 0; i < 8; ++i) { v[i] = __expf(v[i] - mx); s += v[i]; }
        for (int off = 1; off < 64; off <<= 1) s += __shfl_xor(s, off);
        float inv = 1.f / s;
        union { unsigned short h[8]; uint4 u; } pk;
        #pragma unroll
        for (int i = 0; i < 8; ++i) pk.h[i] = f2b(v[i] * inv);
        *(uint4*)(wa + (size_t)wave * Nv + lane * 8) = pk.u;
        return;
    }
    int c = (bid - 8320) * 256 + threadIdx.x;   // chunk of 8 floats
    const float* src; unsigned short* dst; int off;
    if (c < 131072) { src = w1; dst = w1b; off = c; }
    else            { src = w2; dst = w2b; off = c - 131072; }
    float4 a = ((const float4*)src)[off * 2];
    float4 b = ((const float4*)src)[off * 2 + 1];
    union { unsigned short h[8]; uint4 u; } pk;
    pk.h[0] = f2b(a.x); pk.h[1] = f2b(a.y); pk.h[2] = f2b(a.z); pk.h[3] = f2b(a.w);
    pk.h[4] = f2b(b.x); pk.h[5] = f2b(b.y); pk.h[6] = f2b(b.z); pk.h[7] = f2b(b.w);
    ((uint4*)dst)[off] = pk.u;
}

// ---------------- bf16 MFMA GEMM, depth-2 pipelined (3 LDS buffers) ---------
// MODE 0: C[m,n] = A[m,:].W[n,:] + bias[n], f32 out, normal layout
// MODE 2: bf16 out TRANSPOSED to Cv[b][n(d)][tok] (shape [Bv][Dv][Nv]) plus
//         per-(b,d) partial LN sums part[(b*Dv+d)*4 + m_chunk] = (sum, sumsq)
template <int MODE>
__global__ __launch_bounds__(256) void k_gemm(
    const unsigned short* __restrict__ A,   // [M][K] bf16
    const unsigned short* __restrict__ W,   // [Nn][K] bf16
    const float* __restrict__ bias,         // [Nn] f32
    void* __restrict__ Cv,
    float2* __restrict__ part,
    int M, int Nn, int K) {
    __shared__ __align__(16) unsigned short sA[3][128 * 64];
    __shared__ __align__(16) unsigned short sB[3][128 * 64];
    const int t = threadIdx.x;
    const int bn = blockIdx.x * 128;
    const int bm = blockIdx.y * 128;
    const int lane = t & 63;
    const int w = t >> 6, wm = w >> 1, wn = w & 1;
    const int fr = lane & 15, fq = lane >> 4;
    const int NT = K >> 6;
    f32x4 acc[4][4] = {};

#define STAGE(s, k0)                                                        \
    {                                                                       \
        _Pragma("unroll")                                                   \
        for (int i_ = 0; i_ < 4; ++i_) {                                    \
            int c_ = t + i_ * 256;                                          \
            int row_ = c_ >> 3, col_ = c_ & 7;                              \
            int cs_ = col_ ^ (row_ & 7);                                    \
            gld16(A + (size_t)(bm + row_) * K + (k0) + cs_ * 8, &sA[s][c_ * 8]); \
            gld16(W + (size_t)(bn + row_) * K + (k0) + cs_ * 8, &sB[s][c_ * 8]); \
        }                                                                   \
    }

    STAGE(0, 0);
    STAGE(1, 64);
    for (int it = 0; it < NT; ++it) {
        if (it + 2 < NT) {
            STAGE((it + 2) % 3, (it + 2) * 64);
            asm volatile("s_waitcnt vmcnt(16)" ::: "memory");
        } else if (it + 1 < NT) {
            asm volatile("s_waitcnt vmcnt(8)" ::: "memory");
        } else {
            asm volatile("s_waitcnt vmcnt(0)" ::: "memory");
        }
        __builtin_amdgcn_s_barrier();
        const unsigned short* pA = sA[it % 3];
        const unsigned short* pB = sB[it % 3];
        #pragma unroll
        for (int kk = 0; kk < 2; ++kk) {
            short8 af[4], bv[4];
            #pragma unroll
            for (int i = 0; i < 4; ++i)
                af[i] = *(const short8*)&pA[(wm * 64 + i * 16 + fr) * 64 + (((kk << 2) + fq) ^ (fr & 7)) * 8];
            #pragma unroll
            for (int j = 0; j < 4; ++j)
                bv[j] = *(const short8*)&pB[(wn * 64 + j * 16 + fr) * 64 + (((kk << 2) + fq) ^ (fr & 7)) * 8];
            #pragma unroll
            for (int i = 0; i < 4; ++i)
                #pragma unroll
                for (int j = 0; j < 4; ++j)
                    acc[i][j] = __builtin_amdgcn_mfma_f32_16x16x32_bf16(af[i], bv[j], acc[i][j], 0, 0, 0);
        }
        __builtin_amdgcn_s_barrier();
    }
#undef STAGE
    if (MODE == 0) {
        #pragma unroll
        for (int j = 0; j < 4; ++j) {
            const int n = bn + wn * 64 + j * 16 + fr;
            const float bj = bias[n];
            #pragma unroll
            for (int i = 0; i < 4; ++i) {
                const int m0 = bm + wm * 64 + i * 16 + fq * 4;
                #pragma unroll
                for (int r = 0; r < 4; ++r)
                    ((float*)Cv)[(size_t)(m0 + r) * Nn + n] = acc[i][j][r] + bj;
            }
        }
    } else {
        // ---- transposed bf16 tile via LDS (K-loop LDS is dead now) + stats ----
        unsigned short* sc = &sA[0][0];        // [128 d][136 tok] ushort = 34 KB
        float2* red = (float2*)&sB[0][0];      // [128 d][8] partial (s,q) = 8 KB
        const int bB   = bm >> 9;              // batch
        const int tok0 = bm & 511;             // token offset within batch
        const int chunk = (bm >> 7) & 3;       // which 128-token chunk
        #pragma unroll
        for (int j = 0; j < 4; ++j) {
            const int col = wn * 64 + j * 16 + fr;       // local d
            const float bj = bias[bn + col];
            float s = 0.f, q = 0.f;
            #pragma unroll
            for (int i = 0; i < 4; ++i) {
                const int row0 = wm * 64 + i * 16 + fq * 4;  // local token
                #pragma unroll
                for (int r = 0; r < 4; r += 2) {
                    float v0 = acc[i][j][r] + bj;
                    float v1 = acc[i][j][r + 1] + bj;
                    s += v0 + v1;
                    q = fmaf(v0, v0, fmaf(v1, v1, q));
                    unsigned int pk = (unsigned int)f2b(v0) | ((unsigned int)f2b(v1) << 16);
                    *(unsigned int*)&sc[col * 136 + row0 + r] = pk;
                }
            }
            red[col * 8 + wm * 4 + fq] = make_float2(s, q);
        }
        __syncthreads();
        if (t < 128) {
            float S = 0.f, Q = 0.f;
            #pragma unroll
            for (int k = 0; k < 8; ++k) { float2 v = red[t * 8 + k]; S += v.x; Q += v.y; }
            part[((size_t)bB * Dv + bn + t) * 4 + chunk] = make_float2(S, Q);
        }
        unsigned short* dst = (unsigned short*)Cv;
        #pragma unroll
        for (int k = 0; k < 8; ++k) {
            const int c = t + k * 256;
            const int dl = c >> 4, tk = c & 15;
            uint4 v = *(const uint4*)&sc[dl * 136 + tk * 8];
            *(uint4*)&dst[((size_t)bB * Dv + bn + dl) * Nv + tok0 + tk * 8] = v;
        }
    }
}

// ---------------- mixer GEMM: in-block router + blend-in-staging + LN-fold --
// Using sum_n(softmax row)=1:  sum_n xn[d,n]*wa[m,n] = rstd_d*(sum_n xp[d,n]*wa[m,n] - mu_d)
// so B operand is RAW transposed xp; LN applied in epilogue.
__global__ __launch_bounds__(256) void k_mixg(
    const unsigned short* __restrict__ wa,    // [E*H][512][512] bf16 (softmaxed)
    const unsigned short* __restrict__ xpT,   // [8][1024][512] bf16 (raw xp, transposed)
    const float* __restrict__ bias,           // [E][H][512] f32
    const float* __restrict__ xmean,          // [8][1024] f32
    const float* __restrict__ router_w,       // [E][1024] f32
    const float2* __restrict__ part,          // [(b*Dv+d)*4 + chunk] (sum,sumsq)
    unsigned short* __restrict__ y,           // [8][512][1024] bf16
    float* __restrict__ aux_out) {
    __shared__ __align__(16) unsigned short sA[2][128 * 64];
    __shared__ __align__(16) unsigned short sB[2][128 * 64];
    __shared__ float probs[Bv][Ev];
    __shared__ float twsh[Bv][2];
    __shared__ int   tsel[Bv][2];
    __shared__ int   top1s[Bv];
    const int t = threadIdx.x;
    const int bm = blockIdx.x * 128;  // m tile (4)
    const int bh = blockIdx.y;        // 64
    const int b = bh >> 3, h = bh & 7;

    // ---- redundant per-block router: 64 dots (b,e) x 4 lanes each ----
    {
        int pid = t >> 2, l = t & 3;
        int rb = pid >> 3, re = pid & 7;
        const float4* xm = (const float4*)(xmean + rb * Dv);
        const float4* rw = (const float4*)(router_w + re * Dv);
        float s = 0.f;
        #pragma unroll
        for (int j = 0; j < 64; ++j) {
            float4 aa = xm[l + j * 4], ww = rw[l + j * 4];
            s = fmaf(aa.x, ww.x, s); s = fmaf(aa.y, ww.y, s);
            s = fmaf(aa.z, ww.z, s); s = fmaf(aa.w, ww.w, s);
        }
        s += __shfl_xor(s, 1); s += __shfl_xor(s, 2);
        if (l == 0) probs[rb][re] = s;
    }
    __syncthreads();
    if (t < Bv) {
        int bb = t;
        float mx = -1e30f;
        for (int e2 = 0; e2 < Ev; ++e2) mx = fmaxf(mx, probs[bb][e2]);
        float sum = 0.f;
        for (int e2 = 0; e2 < Ev; ++e2) { float v = __expf(probs[bb][e2] - mx); probs[bb][e2] = v; sum += v; }
        float inv = 1.f / sum;
        for (int e2 = 0; e2 < Ev; ++e2) probs[bb][e2] *= inv;
        int i0 = 0; float p0 = probs[bb][0];
        for (int e2 = 1; e2 < Ev; ++e2) if (probs[bb][e2] > p0) { p0 = probs[bb][e2]; i0 = e2; }
        int i1 = -1; float p1 = -1.f;
        for (int e2 = 0; e2 < Ev; ++e2) if (e2 != i0 && probs[bb][e2] > p1) { p1 = probs[bb][e2]; i1 = e2; }
        float s2 = p0 + p1;
        tsel[bb][0] = i0; tsel[bb][1] = i1;
        twsh[bb][0] = p0 / s2; twsh[bb][1] = p1 / s2;
        top1s[bb] = i0;
    }
    __syncthreads();
    if (blockIdx.x == 0 && bh == 0 && t == 0) {
        float aux = 0.f;
        for (int e2 = 0; e2 < Ev; ++e2) {
            float pm = 0.f, mm = 0.f;
            for (int bb = 0; bb < Bv; ++bb) { pm += probs[bb][e2]; mm += (top1s[bb] == e2) ? 1.f : 0.f; }
            aux += (pm / Bv) * (mm / Bv);
        }
        *aux_out = aux * Ev;
    }
    const int e0 = tsel[b][0], e1 = tsel[b][1];
    const float tw0 = twsh[b][0], tw1 = twsh[b][1];

    const int lane = t & 63;
    const int w = t >> 6, wm = w >> 1, wn = w & 1;
    const int fr = lane & 15, fq = lane >> 4;

    // ---- LN stats from gemm1 partials (L2-hot, hidden under staging) ----
    float rstd_j[4], nmr_j[4];
    #pragma unroll
    for (int j = 0; j < 4; ++j) {
        const int dg = h * HDv + wn * 64 + j * 16 + fr;
        const float2* pp = part + ((size_t)b * Dv + dg) * 4;
        float S = 0.f, Q = 0.f;
        #pragma unroll
        for (int cc = 0; cc < 4; ++cc) { float2 v = pp[cc]; S += v.x; Q += v.y; }
        float mu = S * (1.f / Nv);
        float var = Q * (1.f / Nv) - mu * mu;
        float rs = rsqrtf(var + EPSv);
        rstd_j[j] = rs; nmr_j[j] = -mu * rs;
    }

    const unsigned short* A0 = wa + (size_t)(e0 * Hv + h) * Nv * Nv;
    const unsigned short* A1 = wa + (size_t)(e1 * Hv + h) * Nv * Nv;
    const unsigned short* Bb = xpT + ((size_t)b * Dv + h * HDv) * Nv;
    const int NT = Nv >> 6;  // 8
    f32x4 acc[4][4] = {};
    uint4 ra0[4], ra1[4];

#define BSTAGE(s, k0)                                                       \
    {                                                                       \
        _Pragma("unroll")                                                   \
        for (int i_ = 0; i_ < 4; ++i_) {                                    \
            int c_ = t + i_ * 256;                                          \
            int row_ = c_ >> 3, col_ = c_ & 7;                              \
            int cs_ = col_ ^ (row_ & 7);                                    \
            gld16(Bb + (size_t)row_ * Nv + (k0) + cs_ * 8, &sB[s][c_ * 8]); \
        }                                                                   \
    }
#define ALOAD(k0)                                                           \
    {                                                                       \
        _Pragma("unroll")                                                   \
        for (int i_ = 0; i_ < 4; ++i_) {                                    \
            int c_ = t + i_ * 256;                                          \
            int row_ = c_ >> 3, col_ = c_ & 7;                              \
            int cs_ = col_ ^ (row_ & 7);                                    \
            size_t off_ = (size_t)(bm + row_) * Nv + (k0) + cs_ * 8;        \
            ra0[i_] = *(const uint4*)&A0[off_];                             \
            ra1[i_] = *(const uint4*)&A1[off_];                             \
        }                                                                   \
    }

    BSTAGE(0, 0);
    ALOAD(0);
    for (int it = 0; it < NT; ++it) {
        if (it + 1 < NT) {
            BSTAGE((it + 1) & 1, (it + 1) * 64);
            asm volatile("s_waitcnt vmcnt(4)" ::: "memory");
        } else {
            asm volatile("s_waitcnt vmcnt(0)" ::: "memory");
        }
        // blend A regs -> LDS (same linear chunk layout as gld16 staging)
        #pragma unroll
        for (int i = 0; i < 4; ++i) {
            int c = t + i * 256;
            uint4 o;
            o.x = blend2(ra0[i].x, ra1[i].x, tw0, tw1);
            o.y = blend2(ra0[i].y, ra1[i].y, tw0, tw1);
            o.z = blend2(ra0[i].z, ra1[i].z, tw0, tw1);
            o.w = blend2(ra0[i].w, ra1[i].w, tw0, tw1);
            *(uint4*)&sA[it & 1][c * 8] = o;
        }
        if (it + 1 < NT) ALOAD((it + 1) * 64);
        asm volatile("s_waitcnt lgkmcnt(0)" ::: "memory");
        __builtin_amdgcn_s_barrier();
        const unsigned short* pA = sA[it & 1];
        const unsigned short* pB = sB[it & 1];
        #pragma unroll
        for (int kk = 0; kk < 2; ++kk) {
            short8 af[4], bv[4];
            #pragma unroll
            for (int i = 0; i < 4; ++i)
                af[i] = *(const short8*)&pA[(wm * 64 + i * 16 + fr) * 64 + (((kk << 2) + fq) ^ (fr & 7)) * 8];
            #pragma unroll
            for (int j = 0; j < 4; ++j)
                bv[j] = *(const short8*)&pB[(wn * 64 + j * 16 + fr) * 64 + (((kk << 2) + fq) ^ (fr & 7)) * 8];
            #pragma unroll
            for (int i = 0; i < 4; ++i)
                #pragma unroll
                for (int j = 0; j < 4; ++j)
                    acc[i][j] = __builtin_amdgcn_mfma_f32_16x16x32_bf16(af[i], bv[j], acc[i][j], 0, 0, 0);
        }
        __builtin_amdgcn_s_barrier();
    }
#undef BSTAGE
#undef ALOAD
    // epilogue: y = rstd_d*(acc - mu_d) + blended bias
    #pragma unroll
    for (int i = 0; i < 4; ++i) {
        #pragma unroll
        for (int r = 0; r < 4; ++r) {
            const int m = bm + wm * 64 + i * 16 + fq * 4 + r;
            const float br = tw0 * bias[(size_t)(e0 * Hv + h) * Nv + m]
                           + tw1 * bias[(size_t)(e1 * Hv + h) * Nv + m];
            #pragma unroll
            for (int j = 0; j < 4; ++j) {
                const int d = wn * 64 + j * 16 + fr;
                float v = fmaf(acc[i][j][r], rstd_j[j], nmr_j[j] + br);
                y[((size_t)b * Nv + m) * Dv + h * HDv + d] = f2b(v);
            }
        }
    }
}

extern "C" void kernel_launch(void* const* d_in, const int* in_sizes, int n_in,
                              void* d_out, int out_size, void* d_ws, size_t ws_size,
                              hipStream_t stream) {
    const float* x        = (const float*)d_in[0];
    const float* weight   = (const float*)d_in[1];
    const float* bias     = (const float*)d_in[2];
    const float* router_w = (const float*)d_in[3];
    const float* in_w     = (const float*)d_in[4];
    const float* in_b     = (const float*)d_in[5];
    const float* out_w    = (const float*)d_in[6];
    const float* out_b    = (const float*)d_in[7];
    float* out = (float*)d_out;

    if (ws_size < ((size_t)63 << 20)) return;

    char* wsb = (char*)d_ws;
    float*  xmean = (float*)(wsb);                                   // 32 KB
    float2* part  = (float2*)(wsb + 65536);                          // 256 KB
    unsigned short* in_wb  = (unsigned short*)(wsb + ((size_t)1 << 20));   // 2 MB
    unsigned short* out_wb = (unsigned short*)(wsb + ((size_t)3 << 20));   // 2 MB
    unsigned short* xb     = (unsigned short*)(wsb + ((size_t)5 << 20));   // 8 MB (later y)
    unsigned short* xpT    = (unsigned short*)(wsb + ((size_t)13 << 20));  // 8 MB
    unsigned short* wa     = (unsigned short*)(wsb + ((size_t)29 << 20));  // 32 MB
    unsigned short* y = xb;  // xb dead after gemm1

    k_pre<<<9344, 256, 0, stream>>>(x, weight, in_w, out_w, xb, xmean, wa, in_wb, out_wb);
    k_gemm<2><<<dim3(8, 32), 256, 0, stream>>>(xb, in_wb, in_b, xpT, part, Bv * Nv, Dv, Dv);
    k_mixg<<<dim3(4, 64), 256, 0, stream>>>(wa, xpT, bias, xmean, router_w, part, y,
                                            out + (size_t)Bv * Nv * Dv);
    k_gemm<0><<<dim3(8, 32), 256, 0, stream>>>(y, out_wb, out_b, out, nullptr, Bv * Nv, Dv, Dv);
}

// Round 2
// 74.865 us; speedup vs baseline: 1.3162x; 1.0006x over previous
//
#include <hip/hip_runtime.h>
#include <hip/hip_bf16.h>

#define Bv 8
#define Nv 512
#define Dv 1024
#define Ev 8
#define Hv 8
#define HDv 128
#define EPSv 1e-5f

typedef __attribute__((ext_vector_type(8))) short short8;
typedef __attribute__((ext_vector_type(4))) float f32x4;

__device__ __forceinline__ unsigned short f2b(float f) {
    __hip_bfloat16 h = __float2bfloat16(f);
    return *reinterpret_cast<unsigned short*>(&h);
}
__device__ __forceinline__ float bf2f(unsigned int u) {
    union { unsigned int i; float f; } v; v.i = u << 16; return v.f;
}
__device__ __forceinline__ unsigned int blend2(unsigned int a, unsigned int b,
                                               float tw0, float tw1) {
    float lo = tw0 * bf2f(a & 0xffffu) + tw1 * bf2f(b & 0xffffu);
    float hi = tw0 * bf2f(a >> 16)     + tw1 * bf2f(b >> 16);
    return (unsigned int)f2b(lo) | ((unsigned int)f2b(hi) << 16);
}

// async global->LDS, 16 bytes per lane; LDS dest must be linear (base + lane*16)
__device__ __forceinline__ void gld16(const void* g, void* l) {
    __builtin_amdgcn_global_load_lds(
        (const __attribute__((address_space(1))) void*)(uintptr_t)(g),
        (__attribute__((address_space(3))) void*)(uintptr_t)(l), 16, 0, 0);
}

// ---------------- fused preprocessing:
//   blocks [0,128):        cast x->bf16 (coalesced float4 rows) + column partial sums
//   blocks [128,8320):     softmax all E*H*N weight rows -> wa bf16
//   blocks [8320,9344):    cast in_w/out_w -> bf16
__global__ __launch_bounds__(256) void k_pre(const float* __restrict__ x,
                                             const float* __restrict__ weight,
                                             const float* __restrict__ w1,
                                             const float* __restrict__ w2,
                                             unsigned short* __restrict__ xb,
                                             float* __restrict__ part_x,
                                             unsigned short* __restrict__ wa,
                                             unsigned short* __restrict__ w1b,
                                             unsigned short* __restrict__ w2b) {
    int bid = blockIdx.x;
    int t = threadIdx.x;
    if (bid < 128) {
        // (b, chunk of 32 rows); 256 threads x float4 = one full D row per iter
        int b = bid >> 4, c = bid & 15;
        const float* px = x + ((size_t)b * Nv + c * 32) * Dv + t * 4;
        unsigned short* qx = xb + ((size_t)b * Nv + c * 32) * Dv + t * 4;
        float4 s4 = make_float4(0.f, 0.f, 0.f, 0.f);
        #pragma unroll 8
        for (int r = 0; r < 32; ++r) {
            float4 v = *(const float4*)(px + (size_t)r * Dv);
            s4.x += v.x; s4.y += v.y; s4.z += v.z; s4.w += v.w;
            uint2 pk;
            pk.x = (unsigned)f2b(v.x) | ((unsigned)f2b(v.y) << 16);
            pk.y = (unsigned)f2b(v.z) | ((unsigned)f2b(v.w) << 16);
            *(uint2*)(qx + (size_t)r * Dv) = pk;
        }
        *(float4*)(part_x + ((size_t)(b * 16 + c)) * Dv + t * 4) = s4;
        return;
    }
    if (bid < 128 + 8192) {
        int wave = (bid - 128) * 4 + (t >> 6);  // row over E*H*N = 32768
        int lane = t & 63;
        const float* row = weight + (size_t)wave * Nv;
        const float4* r4 = (const float4*)(row + lane * 8);
        float4 a = r4[0], b = r4[1];
        float v[8] = {a.x, a.y, a.z, a.w, b.x, b.y, b.z, b.w};
        float mx = v[0];
        #pragma unroll
        for (int i = 1; i < 8; ++i) mx = fmaxf(mx, v[i]);
        for (int off = 1; off < 64; off <<= 1) mx = fmaxf(mx, __shfl_xor(mx, off));
        float s = 0.f;
        #pragma unroll
        for (int i = 0; i < 8; ++i) { v[i] = __expf(v[i] - mx); s += v[i]; }
        for (int off = 1; off < 64; off <<= 1) s += __shfl_xor(s, off);
        float inv = 1.f / s;
        union { unsigned short h[8]; uint4 u; } pk;
        #pragma unroll
        for (int i = 0; i < 8; ++i) pk.h[i] = f2b(v[i] * inv);
        *(uint4*)(wa + (size_t)wave * Nv + lane * 8) = pk.u;
        return;
    }
    int c = (bid - 8320) * 256 + t;   // chunk of 8 floats
    const float* src; unsigned short* dst; int off;
    if (c < 131072) { src = w1; dst = w1b; off = c; }
    else            { src = w2; dst = w2b; off = c - 131072; }
    float4 a = ((const float4*)src)[off * 2];
    float4 b = ((const float4*)src)[off * 2 + 1];
    union { unsigned short h[8]; uint4 u; } pk;
    pk.h[0] = f2b(a.x); pk.h[1] = f2b(a.y); pk.h[2] = f2b(a.z); pk.h[3] = f2b(a.w);
    pk.h[4] = f2b(b.x); pk.h[5] = f2b(b.y); pk.h[6] = f2b(b.z); pk.h[7] = f2b(b.w);
    ((uint4*)dst)[off] = pk.u;
}

// ---------------- bf16 MFMA GEMM, depth-2 pipelined (3 LDS buffers) ---------
// MODE 0: C[m,n] = A[m,:].W[n,:] + bias[n], f32 out, normal layout
// MODE 2: bf16 out TRANSPOSED to Cv[b][n(d)][tok] (shape [Bv][Dv][Nv]) plus
//         per-(b,d) partial LN sums part[(b*Dv+d)*4 + m_chunk] = (sum, sumsq);
//         also reduces part_x -> xmean (overlapped with staging prologue)
template <int MODE>
__global__ __launch_bounds__(256) void k_gemm(
    const unsigned short* __restrict__ A,   // [M][K] bf16
    const unsigned short* __restrict__ W,   // [Nn][K] bf16
    const float* __restrict__ bias,         // [Nn] f32
    void* __restrict__ Cv,
    float2* __restrict__ part,
    const float* __restrict__ part_x,
    float* __restrict__ xmean,
    int M, int Nn, int K) {
    __shared__ __align__(16) unsigned short sA[3][128 * 64];
    __shared__ __align__(16) unsigned short sB[3][128 * 64];
    const int t = threadIdx.x;
    const int bn = blockIdx.x * 128;
    const int bm = blockIdx.y * 128;
    const int lane = t & 63;
    const int w = t >> 6, wm = w >> 1, wn = w & 1;
    const int fr = lane & 15, fq = lane >> 4;
    const int NT = K >> 6;
    f32x4 acc[4][4] = {};

#define STAGE(s, k0)                                                        \
    {                                                                       \
        _Pragma("unroll")                                                   \
        for (int i_ = 0; i_ < 4; ++i_) {                                    \
            int c_ = t + i_ * 256;                                          \
            int row_ = c_ >> 3, col_ = c_ & 7;                              \
            int cs_ = col_ ^ (row_ & 7);                                    \
            gld16(A + (size_t)(bm + row_) * K + (k0) + cs_ * 8, &sA[s][c_ * 8]); \
            gld16(W + (size_t)(bn + row_) * K + (k0) + cs_ * 8, &sB[s][c_ * 8]); \
        }                                                                   \
    }

    STAGE(0, 0);
    STAGE(1, 64);
    if (MODE == 2) {
        // xmean reduce: 256 blocks x 32 outputs, overlapped with async staging
        int blk = blockIdx.y * 8 + blockIdx.x;      // 0..255
        int o = blk * 32 + (t >> 3);                // output idx over 8192
        int c2 = t & 7;
        int b2 = o >> 10, d2 = o & 1023;
        float S = part_x[((size_t)(b2 * 16 + c2)) * Dv + d2]
                + part_x[((size_t)(b2 * 16 + c2 + 8)) * Dv + d2];
        S += __shfl_xor(S, 1); S += __shfl_xor(S, 2); S += __shfl_xor(S, 4);
        if (c2 == 0) xmean[o] = S * (1.f / Nv);
    }
    for (int it = 0; it < NT; ++it) {
        if (it + 2 < NT) {
            STAGE((it + 2) % 3, (it + 2) * 64);
            asm volatile("s_waitcnt vmcnt(16)" ::: "memory");
        } else if (it + 1 < NT) {
            asm volatile("s_waitcnt vmcnt(8)" ::: "memory");
        } else {
            asm volatile("s_waitcnt vmcnt(0)" ::: "memory");
        }
        __builtin_amdgcn_s_barrier();
        const unsigned short* pA = sA[it % 3];
        const unsigned short* pB = sB[it % 3];
        #pragma unroll
        for (int kk = 0; kk < 2; ++kk) {
            short8 af[4], bv[4];
            #pragma unroll
            for (int i = 0; i < 4; ++i)
                af[i] = *(const short8*)&pA[(wm * 64 + i * 16 + fr) * 64 + (((kk << 2) + fq) ^ (fr & 7)) * 8];
            #pragma unroll
            for (int j = 0; j < 4; ++j)
                bv[j] = *(const short8*)&pB[(wn * 64 + j * 16 + fr) * 64 + (((kk << 2) + fq) ^ (fr & 7)) * 8];
            #pragma unroll
            for (int i = 0; i < 4; ++i)
                #pragma unroll
                for (int j = 0; j < 4; ++j)
                    acc[i][j] = __builtin_amdgcn_mfma_f32_16x16x32_bf16(af[i], bv[j], acc[i][j], 0, 0, 0);
        }
        __builtin_amdgcn_s_barrier();
    }
#undef STAGE
    if (MODE == 0) {
        #pragma unroll
        for (int j = 0; j < 4; ++j) {
            const int n = bn + wn * 64 + j * 16 + fr;
            const float bj = bias[n];
            #pragma unroll
            for (int i = 0; i < 4; ++i) {
                const int m0 = bm + wm * 64 + i * 16 + fq * 4;
                #pragma unroll
                for (int r = 0; r < 4; ++r)
                    ((float*)Cv)[(size_t)(m0 + r) * Nn + n] = acc[i][j][r] + bj;
            }
        }
    } else {
        // ---- transposed bf16 tile via LDS (K-loop LDS is dead now) + stats ----
        unsigned short* sc = &sA[0][0];        // [128 d][136 tok] ushort = 34 KB
        float2* red = (float2*)&sB[0][0];      // [128 d][8] partial (s,q) = 8 KB
        const int bB   = bm >> 9;              // batch
        const int tok0 = bm & 511;             // token offset within batch
        const int chunk = (bm >> 7) & 3;       // which 128-token chunk
        #pragma unroll
        for (int j = 0; j < 4; ++j) {
            const int col = wn * 64 + j * 16 + fr;       // local d
            const float bj = bias[bn + col];
            float s = 0.f, q = 0.f;
            #pragma unroll
            for (int i = 0; i < 4; ++i) {
                const int row0 = wm * 64 + i * 16 + fq * 4;  // local token
                #pragma unroll
                for (int r = 0; r < 4; r += 2) {
                    float v0 = acc[i][j][r] + bj;
                    float v1 = acc[i][j][r + 1] + bj;
                    s += v0 + v1;
                    q = fmaf(v0, v0, fmaf(v1, v1, q));
                    unsigned int pk = (unsigned int)f2b(v0) | ((unsigned int)f2b(v1) << 16);
                    *(unsigned int*)&sc[col * 136 + row0 + r] = pk;
                }
            }
            red[col * 8 + wm * 4 + fq] = make_float2(s, q);
        }
        __syncthreads();
        if (t < 128) {
            float S = 0.f, Q = 0.f;
            #pragma unroll
            for (int k = 0; k < 8; ++k) { float2 v = red[t * 8 + k]; S += v.x; Q += v.y; }
            part[((size_t)bB * Dv + bn + t) * 4 + chunk] = make_float2(S, Q);
        }
        unsigned short* dst = (unsigned short*)Cv;
        #pragma unroll
        for (int k = 0; k < 8; ++k) {
            const int c = t + k * 256;
            const int dl = c >> 4, tk = c & 15;
            uint4 v = *(const uint4*)&sc[dl * 136 + tk * 8];
            *(uint4*)&dst[((size_t)bB * Dv + bn + dl) * Nv + tok0 + tk * 8] = v;
        }
    }
}

// ---------------- mixer GEMM: in-block router + blend-in-staging + LN-fold --
// Using sum_n(softmax row)=1:  sum_n xn[d,n]*wa[m,n] = rstd_d*(sum_n xp[d,n]*wa[m,n] - mu_d)
// so B operand is RAW transposed xp; LN applied in epilogue.
__global__ __launch_bounds__(256) void k_mixg(
    const unsigned short* __restrict__ wa,    // [E*H][512][512] bf16 (softmaxed)
    const unsigned short* __restrict__ xpT,   // [8][1024][512] bf16 (raw xp, transposed)
    const float* __restrict__ bias,           // [E][H][512] f32
    const float* __restrict__ xmean,          // [8][1024] f32
    const float* __restrict__ router_w,       // [E][1024] f32
    const float2* __restrict__ part,          // [(b*Dv+d)*4 + chunk] (sum,sumsq)
    unsigned short* __restrict__ y,           // [8][512][1024] bf16
    float* __restrict__ aux_out) {
    __shared__ __align__(16) unsigned short sA[2][128 * 64];
    __shared__ __align__(16) unsigned short sB[2][128 * 64];
    __shared__ float probs[Bv][Ev];
    __shared__ float twsh[Bv][2];
    __shared__ int   tsel[Bv][2];
    __shared__ int   top1s[Bv];
    const int t = threadIdx.x;
    const int bm = blockIdx.x * 128;  // m tile (4)
    const int bh = blockIdx.y;        // 64
    const int b = bh >> 3, h = bh & 7;

    // ---- redundant per-block router: 64 dots (b,e) x 4 lanes each ----
    {
        int pid = t >> 2, l = t & 3;
        int rb = pid >> 3, re = pid & 7;
        const float4* xm = (const float4*)(xmean + rb * Dv);
        const float4* rw = (const float4*)(router_w + re * Dv);
        float s = 0.f;
        #pragma unroll
        for (int j = 0; j < 64; ++j) {
            float4 aa = xm[l + j * 4], ww = rw[l + j * 4];
            s = fmaf(aa.x, ww.x, s); s = fmaf(aa.y, ww.y, s);
            s = fmaf(aa.z, ww.z, s); s = fmaf(aa.w, ww.w, s);
        }
        s += __shfl_xor(s, 1); s += __shfl_xor(s, 2);
        if (l == 0) probs[rb][re] = s;
    }
    __syncthreads();
    if (t < Bv) {
        int bb = t;
        float mx = -1e30f;
        for (int e2 = 0; e2 < Ev; ++e2) mx = fmaxf(mx, probs[bb][e2]);
        float sum = 0.f;
        for (int e2 = 0; e2 < Ev; ++e2) { float v = __expf(probs[bb][e2] - mx); probs[bb][e2] = v; sum += v; }
        float inv = 1.f / sum;
        for (int e2 = 0; e2 < Ev; ++e2) probs[bb][e2] *= inv;
        int i0 = 0; float p0 = probs[bb][0];
        for (int e2 = 1; e2 < Ev; ++e2) if (probs[bb][e2] > p0) { p0 = probs[bb][e2]; i0 = e2; }
        int i1 = -1; float p1 = -1.f;
        for (int e2 = 0; e2 < Ev; ++e2) if (e2 != i0 && probs[bb][e2] > p1) { p1 = probs[bb][e2]; i1 = e2; }
        float s2 = p0 + p1;
        tsel[bb][0] = i0; tsel[bb][1] = i1;
        twsh[bb][0] = p0 / s2; twsh[bb][1] = p1 / s2;
        top1s[bb] = i0;
    }
    __syncthreads();
    if (blockIdx.x == 0 && bh == 0 && t == 0) {
        float aux = 0.f;
        for (int e2 = 0; e2 < Ev; ++e2) {
            float pm = 0.f, mm = 0.f;
            for (int bb = 0; bb < Bv; ++bb) { pm += probs[bb][e2]; mm += (top1s[bb] == e2) ? 1.f : 0.f; }
            aux += (pm / Bv) * (mm / Bv);
        }
        *aux_out = aux * Ev;
    }
    const int e0 = tsel[b][0], e1 = tsel[b][1];
    const float tw0 = twsh[b][0], tw1 = twsh[b][1];

    const int lane = t & 63;
    const int w = t >> 6, wm = w >> 1, wn = w & 1;
    const int fr = lane & 15, fq = lane >> 4;

    // ---- LN stats from gemm1 partials (L2-hot, hidden under staging) ----
    float rstd_j[4], nmr_j[4];
    #pragma unroll
    for (int j = 0; j < 4; ++j) {
        const int dg = h * HDv + wn * 64 + j * 16 + fr;
        const float2* pp = part + ((size_t)b * Dv + dg) * 4;
        float S = 0.f, Q = 0.f;
        #pragma unroll
        for (int cc = 0; cc < 4; ++cc) { float2 v = pp[cc]; S += v.x; Q += v.y; }
        float mu = S * (1.f / Nv);
        float var = Q * (1.f / Nv) - mu * mu;
        float rs = rsqrtf(var + EPSv);
        rstd_j[j] = rs; nmr_j[j] = -mu * rs;
    }

    const unsigned short* A0 = wa + (size_t)(e0 * Hv + h) * Nv * Nv;
    const unsigned short* A1 = wa + (size_t)(e1 * Hv + h) * Nv * Nv;
    const unsigned short* Bb = xpT + ((size_t)b * Dv + h * HDv) * Nv;
    const int NT = Nv >> 6;  // 8
    f32x4 acc[4][4] = {};
    uint4 ra0[4], ra1[4];

#define BSTAGE(s, k0)                                                       \
    {                                                                       \
        _Pragma("unroll")                                                   \
        for (int i_ = 0; i_ < 4; ++i_) {                                    \
            int c_ = t + i_ * 256;                                          \
            int row_ = c_ >> 3, col_ = c_ & 7;                              \
            int cs_ = col_ ^ (row_ & 7);                                    \
            gld16(Bb + (size_t)row_ * Nv + (k0) + cs_ * 8, &sB[s][c_ * 8]); \
        }                                                                   \
    }
#define ALOAD(k0)                                                           \
    {                                                                       \
        _Pragma("unroll")                                                   \
        for (int i_ = 0; i_ < 4; ++i_) {                                    \
            int c_ = t + i_ * 256;                                          \
            int row_ = c_ >> 3, col_ = c_ & 7;                              \
            int cs_ = col_ ^ (row_ & 7);                                    \
            size_t off_ = (size_t)(bm + row_) * Nv + (k0) + cs_ * 8;        \
            ra0[i_] = *(const uint4*)&A0[off_];                             \
            ra1[i_] = *(const uint4*)&A1[off_];                             \
        }                                                                   \
    }

    BSTAGE(0, 0);
    ALOAD(0);
    for (int it = 0; it < NT; ++it) {
        if (it + 1 < NT) {
            BSTAGE((it + 1) & 1, (it + 1) * 64);
            asm volatile("s_waitcnt vmcnt(4)" ::: "memory");
        } else {
            asm volatile("s_waitcnt vmcnt(0)" ::: "memory");
        }
        // blend A regs -> LDS (same linear chunk layout as gld16 staging)
        #pragma unroll
        for (int i = 0; i < 4; ++i) {
            int c = t + i * 256;
            uint4 o;
            o.x = blend2(ra0[i].x, ra1[i].x, tw0, tw1);
            o.y = blend2(ra0[i].y, ra1[i].y, tw0, tw1);
            o.z = blend2(ra0[i].z, ra1[i].z, tw0, tw1);
            o.w = blend2(ra0[i].w, ra1[i].w, tw0, tw1);
            *(uint4*)&sA[it & 1][c * 8] = o;
        }
        if (it + 1 < NT) ALOAD((it + 1) * 64);
        asm volatile("s_waitcnt lgkmcnt(0)" ::: "memory");
        __builtin_amdgcn_s_barrier();
        const unsigned short* pA = sA[it & 1];
        const unsigned short* pB = sB[it & 1];
        #pragma unroll
        for (int kk = 0; kk < 2; ++kk) {
            short8 af[4], bv[4];
            #pragma unroll
            for (int i = 0; i < 4; ++i)
                af[i] = *(const short8*)&pA[(wm * 64 + i * 16 + fr) * 64 + (((kk << 2) + fq) ^ (fr & 7)) * 8];
            #pragma unroll
            for (int j = 0; j < 4; ++j)
                bv[j] = *(const short8*)&pB[(wn * 64 + j * 16 + fr) * 64 + (((kk << 2) + fq) ^ (fr & 7)) * 8];
            #pragma unroll
            for (int i = 0; i < 4; ++i)
                #pragma unroll
                for (int j = 0; j < 4; ++j)
                    acc[i][j] = __builtin_amdgcn_mfma_f32_16x16x32_bf16(af[i], bv[j], acc[i][j], 0, 0, 0);
        }
        __builtin_amdgcn_s_barrier();
    }
#undef BSTAGE
#undef ALOAD
    // epilogue: y = rstd_d*(acc - mu_d) + blended bias
    #pragma unroll
    for (int i = 0; i < 4; ++i) {
        #pragma unroll
        for (int r = 0; r < 4; ++r) {
            const int m = bm + wm * 64 + i * 16 + fq * 4 + r;
            const float br = tw0 * bias[(size_t)(e0 * Hv + h) * Nv + m]
                           + tw1 * bias[(size_t)(e1 * Hv + h) * Nv + m];
            #pragma unroll
            for (int j = 0; j < 4; ++j) {
                const int d = wn * 64 + j * 16 + fr;
                float v = fmaf(acc[i][j][r], rstd_j[j], nmr_j[j] + br);
                y[((size_t)b * Nv + m) * Dv + h * HDv + d] = f2b(v);
            }
        }
    }
}

extern "C" void kernel_launch(void* const* d_in, const int* in_sizes, int n_in,
                              void* d_out, int out_size, void* d_ws, size_t ws_size,
                              hipStream_t stream) {
    const float* x        = (const float*)d_in[0];
    const float* weight   = (const float*)d_in[1];
    const float* bias     = (const float*)d_in[2];
    const float* router_w = (const float*)d_in[3];
    const float* in_w     = (const float*)d_in[4];
    const float* in_b     = (const float*)d_in[5];
    const float* out_w    = (const float*)d_in[6];
    const float* out_b    = (const float*)d_in[7];
    float* out = (float*)d_out;

    if (ws_size < ((size_t)63 << 20)) return;

    char* wsb = (char*)d_ws;
    float*  xmean  = (float*)(wsb);                                  // 32 KB
    float2* part   = (float2*)(wsb + 65536);                         // 256 KB
    float*  part_x = (float*)(wsb + 327680);                         // 512 KB
    unsigned short* in_wb  = (unsigned short*)(wsb + ((size_t)1 << 20));   // 2 MB
    unsigned short* out_wb = (unsigned short*)(wsb + ((size_t)3 << 20));   // 2 MB
    unsigned short* xb     = (unsigned short*)(wsb + ((size_t)5 << 20));   // 8 MB (later y)
    unsigned short* xpT    = (unsigned short*)(wsb + ((size_t)13 << 20));  // 8 MB
    unsigned short* wa     = (unsigned short*)(wsb + ((size_t)29 << 20));  // 32 MB
    unsigned short* y = xb;  // xb dead after gemm1

    k_pre<<<9344, 256, 0, stream>>>(x, weight, in_w, out_w, xb, part_x, wa, in_wb, out_wb);
    k_gemm<2><<<dim3(8, 32), 256, 0, stream>>>(xb, in_wb, in_b, xpT, part, part_x, xmean,
                                               Bv * Nv, Dv, Dv);
    k_mixg<<<dim3(4, 64), 256, 0, stream>>>(wa, xpT, bias, xmean, router_w, part, y,
                                            out + (size_t)Bv * Nv * Dv);
    k_gemm<0><<<dim3(8, 32), 256, 0, stream>>>(y, out_wb, out_b, out, nullptr, nullptr, nullptr,
                                               Bv * Nv, Dv, Dv);
}